// Round 6
// baseline (79.657 us; speedup 1.0000x reference)
//
#include <hip/hip_runtime.h>

// DiversityLoss: reference collapses to
//   out = (||colsum||^2 - B * sum(x^2)) / (D * B * (B-1))
// B=64, D=3*256*256=196608. Single memory-bound pass over 50.3 MB fp32.
//
// Round 6: row-front sweep. All previous layouts parked each block on a
// narrow column window and hopped rows at 786 KB stride -> device footprint
// = hundreds of scattered 1-4 KB windows, DRAM page miss per hop, ~2.4 TB/s
// (occupancy/burst-width/nt/fusion theories all measured dead in R2-R5).
// The 6.3 TB/s references (ws fill, m13 copy) sweep ONE contiguous front.
// Now: one thread per float4-column (256 blocks x 192 thr = 49152 = D4),
// grid fully co-resident on 256 CUs; per iteration the whole grid reads one
// contiguous 786 KB row, then steps to the next -> spatially a linear copy.
// Each thread owns a full column: no LDS combine, unroll-16 for 16 loads in
// flight per thread. Deterministic partials + tiny finalize (no atomics).

#define NBLK 256
#define NTHR 192   // NBLK * NTHR == D4 == 49152 float4 columns

__global__ __launch_bounds__(NTHR) void div_main(const float4* __restrict__ x4,
                                                 float* __restrict__ partial,
                                                 int D4) {
    const int col = blockIdx.x * NTHR + threadIdx.x;   // one f4-column per thread
    const float4* p = x4 + col;

    float4 acc = make_float4(0.f, 0.f, 0.f, 0.f);
    float sq = 0.f;

    #pragma unroll 16
    for (int r = 0; r < 64; ++r) {
        float4 v = p[(size_t)r * (size_t)D4];
        acc.x += v.x; acc.y += v.y; acc.z += v.z; acc.w += v.w;
        sq = fmaf(v.x, v.x, sq);
        sq = fmaf(v.y, v.y, sq);
        sq = fmaf(v.z, v.z, sq);
        sq = fmaf(v.w, v.w, sq);
    }

    // Thread holds the COMPLETE column sum for its 4 columns.
    float contrib = acc.x * acc.x + acc.y * acc.y + acc.z * acc.z + acc.w * acc.w
                  - 64.0f * sq;

    // Block reduction: wave-64 shuffle, then 3 wave results via LDS.
    #pragma unroll
    for (int off = 32; off > 0; off >>= 1)
        contrib += __shfl_down(contrib, off, 64);

    __shared__ float wsum[3];
    const int wave = threadIdx.x >> 6;
    if ((threadIdx.x & 63) == 0) wsum[wave] = contrib;
    __syncthreads();
    if (threadIdx.x == 0)
        partial[blockIdx.x] = wsum[0] + wsum[1] + wsum[2];
}

__global__ __launch_bounds__(256) void div_finalize(const float* __restrict__ partial,
                                                    float* __restrict__ out,
                                                    float scale) {
    const int t = threadIdx.x;
    float v = partial[t];    // exactly NBLK == 256 partials

    #pragma unroll
    for (int off = 32; off > 0; off >>= 1)
        v += __shfl_down(v, off, 64);

    __shared__ float wsum[4];
    if ((t & 63) == 0) wsum[t >> 6] = v;
    __syncthreads();
    if (t == 0)
        out[0] = (wsum[0] + wsum[1] + wsum[2] + wsum[3]) * scale;
}

extern "C" void kernel_launch(void* const* d_in, const int* in_sizes, int n_in,
                              void* d_out, int out_size, void* d_ws, size_t ws_size,
                              hipStream_t stream) {
    const float* x = (const float*)d_in[0];
    float* out = (float*)d_out;
    float* partial = (float*)d_ws;

    const int B = 64;
    const int total = in_sizes[0];          // 12,582,912 elements
    const int D = total / B;                // 196,608
    const int D4 = D / 4;                   // 49,152

    const float scale = (float)(1.0 / ((double)D * (double)B * (double)(B - 1)));

    div_main<<<NBLK, NTHR, 0, stream>>>((const float4*)x, partial, D4);
    div_finalize<<<1, 256, 0, stream>>>(partial, out, scale);
}